// Round 1
// baseline (9415.099 us; speedup 1.0000x reference)
//
#include <hip/hip_runtime.h>
#include <hip/hip_bf16.h>

// LightGCN propagation on MI355X.
// N_NODES = 150000, D = 64, 3 layers.
// x_{l+1} = normalize(A_norm @ x_l); out = in + sum_l x_{l+1}/(l+1)
//
// SpMM: push-style atomic scatter (16 threads per edge, float4 gather).
// Normalize+accumulate: 1 wave (64 lanes) per row, shfl reduction.

constexpr int N_NODES = 150000;
constexpr int D = 64;
constexpr float NORM_EPS = 1e-12f;

__global__ __launch_bounds__(256) void spmm_scatter(
    const float* __restrict__ x,      // [N, 64] input embeddings for this layer
    const int* __restrict__ rows,
    const int* __restrict__ cols,
    const float* __restrict__ vals,
    float* __restrict__ xnew,         // [N, 64] accumulation target (pre-zeroed)
    int E)
{
    int t = blockIdx.x * blockDim.x + threadIdx.x;
    int e = t >> 4;           // 16 threads per edge
    if (e >= E) return;
    int sub = t & 15;         // which float4 of the 64-dim row

    int r = rows[e];
    int c = cols[e];
    float v = vals[e];

    const float4 xi = *reinterpret_cast<const float4*>(x + (size_t)c * D + sub * 4);
    float* dst = xnew + (size_t)r * D + sub * 4;
    atomicAdd(dst + 0, v * xi.x);
    atomicAdd(dst + 1, v * xi.y);
    atomicAdd(dst + 2, v * xi.z);
    atomicAdd(dst + 3, v * xi.w);
}

// In-place row L2-normalize of xnew, plus out-accumulate.
// 256 threads per block = 4 rows, 64 lanes (1 wave) per row.
__global__ __launch_bounds__(256) void norm_acc(
    float* __restrict__ xnew,          // in: A@x, out: normalized x (in place)
    const float* __restrict__ init,    // in_embs (used when first != 0)
    float* __restrict__ out,           // accumulator
    float invl,                        // 1/(layer+1)
    int first)
{
    int row = blockIdx.x * 4 + (threadIdx.x >> 6);
    if (row >= N_NODES) return;
    int lane = threadIdx.x & 63;
    size_t idx = (size_t)row * D + lane;

    float v = xnew[idx];
    float ss = v * v;
    #pragma unroll
    for (int o = 32; o > 0; o >>= 1)
        ss += __shfl_xor(ss, o);
    float n = sqrtf(ss);
    float xn = v / fmaxf(n, NORM_EPS);

    xnew[idx] = xn;
    float base = first ? init[idx] : out[idx];
    out[idx] = base + xn * invl;
}

extern "C" void kernel_launch(void* const* d_in, const int* in_sizes, int n_in,
                              void* d_out, int out_size, void* d_ws, size_t ws_size,
                              hipStream_t stream) {
    const float* in_embs = (const float*)d_in[0];
    const int*   rows    = (const int*)d_in[1];
    const int*   cols    = (const int*)d_in[2];
    const float* vals    = (const float*)d_in[3];
    float* out = (float*)d_out;

    const int E = in_sizes[1];
    const size_t buf_elems = (size_t)N_NODES * D;
    const size_t buf_bytes = buf_elems * sizeof(float);

    float* bufA = (float*)d_ws;                  // normalized x from previous layer
    float* bufB = (float*)((char*)d_ws + buf_bytes); // SpMM accumulation target

    const int scatter_threads = 256;
    const int scatter_blocks  = (int)(((size_t)E * 16 + scatter_threads - 1) / scatter_threads);
    const int norm_blocks     = (N_NODES + 3) / 4;

    const float* xin = in_embs;
    float* xprev = bufA;
    float* xacc  = bufB;

    for (int layer = 0; layer < 3; ++layer) {
        hipMemsetAsync(xacc, 0, buf_bytes, stream);
        spmm_scatter<<<scatter_blocks, scatter_threads, 0, stream>>>(
            xin, rows, cols, vals, xacc, E);
        norm_acc<<<norm_blocks, 256, 0, stream>>>(
            xacc, in_embs, out, 1.0f / (layer + 1), layer == 0 ? 1 : 0);
        // normalized result now lives in xacc; it becomes next layer's input
        xin = xacc;
        float* t = xprev; xprev = xacc; xacc = t;
    }
}

// Round 2
// 1361.252 us; speedup vs baseline: 6.9165x; 6.9165x over previous
//
#include <hip/hip_runtime.h>
#include <hip/hip_bf16.h>

// LightGCN propagation on MI355X — round 2.
// Pull-based CSR SpMM (no float atomics), fused normalize + accumulate.
//
// Pipeline per kernel_launch (deterministic, rebuilt every call):
//   1. memset counts(=cursor) to 0
//   2. histogram rows -> counts
//   3. single-block scan -> row_ptr (exclusive), cursor copy
//   4. dinv[i] = rsqrt(deg + 1e-7)
//   5. scatter edges into csr_col via cursor atomics (int, cheap)
//   6. 3x fused spmm+normalize+out-accumulate (1 wave per row, lane = dim)

constexpr int N_NODES = 150000;
constexpr int D = 64;

__global__ __launch_bounds__(256) void hist_kernel(
    const int* __restrict__ rows, int* __restrict__ counts, int E)
{
    int i = blockIdx.x * blockDim.x + threadIdx.x;
    if (i < E) atomicAdd(&counts[rows[i]], 1);
}

// Single-block scan over n ints. 1024 threads, 16 waves.
// counts (in) -> row_ptr/cursor (exclusive prefix); row_ptr[n] = total.
__global__ __launch_bounds__(1024) void scan_kernel(
    const int* __restrict__ counts, int* __restrict__ row_ptr,
    int* __restrict__ cursor, int n)
{
    __shared__ int wsum[16];
    __shared__ int woff[17];
    __shared__ int s_running;
    const int tid = threadIdx.x;
    const int lane = tid & 63;
    const int w = tid >> 6;
    if (tid == 0) s_running = 0;
    __syncthreads();

    for (int base = 0; base < n; base += 1024) {
        int i = base + tid;
        int v = (i < n) ? counts[i] : 0;
        // wave-level inclusive scan
        int incl = v;
        #pragma unroll
        for (int off = 1; off < 64; off <<= 1) {
            int t = __shfl_up(incl, off);
            if (lane >= off) incl += t;
        }
        if (lane == 63) wsum[w] = incl;
        __syncthreads();                       // B1: wsum ready
        if (tid < 16) {
            int s = wsum[tid];
            int si = s;
            #pragma unroll
            for (int off = 1; off < 16; off <<= 1) {
                int t = __shfl_up(si, off);
                if (tid >= off) si += t;
            }
            woff[tid] = si - s;                // exclusive wave offset
            if (tid == 15) woff[16] = si;      // chunk total
        }
        __syncthreads();                       // B2: woff ready
        int excl = s_running + woff[w] + (incl - v);
        if (i < n) { row_ptr[i] = excl; cursor[i] = excl; }
        __syncthreads();                       // B3: all reads of s_running done
        if (tid == 0) s_running += woff[16];
        // next read of s_running / write of woff is after the next B1/B2 -> safe
    }
    __syncthreads();
    if (tid == 0) row_ptr[n] = s_running;
}

__global__ __launch_bounds__(256) void dinv_kernel(
    const int* __restrict__ row_ptr, float* __restrict__ dinv, int n)
{
    int i = blockIdx.x * blockDim.x + threadIdx.x;
    if (i < n) {
        float deg = (float)(row_ptr[i + 1] - row_ptr[i]);
        dinv[i] = rsqrtf(deg + 1e-7f);
    }
}

__global__ __launch_bounds__(256) void scatter_kernel(
    const int* __restrict__ rows, const int* __restrict__ cols,
    int* __restrict__ cursor, int* __restrict__ csr_col, int E)
{
    int i = blockIdx.x * blockDim.x + threadIdx.x;
    if (i < E) {
        int r = rows[i];
        int pos = atomicAdd(&cursor[r], 1);
        csr_col[pos] = cols[i];
    }
}

// Fused SpMM + L2-normalize + out accumulate.
// 256 threads = 4 waves = 4 rows; lane = embedding dim.
__global__ __launch_bounds__(256) void spmm_norm(
    const float* __restrict__ x,        // [N, 64] previous layer
    const int* __restrict__ row_ptr,
    const int* __restrict__ csr_col,
    const float* __restrict__ dinv,
    const float* __restrict__ init,     // in_embs
    float* __restrict__ xnew,           // [N, 64] normalized output
    float* __restrict__ out,            // accumulator (d_out)
    float invl, int first)
{
    int row = blockIdx.x * 4 + (threadIdx.x >> 6);
    if (row >= N_NODES) return;
    int lane = threadIdx.x & 63;

    int beg = row_ptr[row];
    int end = row_ptr[row + 1];
    float dr = dinv[row];

    float acc = 0.f;
    for (int j = beg; j < end; ++j) {
        int c = csr_col[j];
        float w = dinv[c];
        acc += w * x[(size_t)c * D + lane];
    }
    acc *= dr;

    float ss = acc * acc;
    #pragma unroll
    for (int off = 32; off > 0; off >>= 1)
        ss += __shfl_xor(ss, off);
    float nrm = sqrtf(ss);
    float xn = acc / fmaxf(nrm, 1e-12f);

    size_t idx = (size_t)row * D + lane;
    xnew[idx] = xn;
    out[idx] = (first ? init[idx] : out[idx]) + xn * invl;
}

extern "C" void kernel_launch(void* const* d_in, const int* in_sizes, int n_in,
                              void* d_out, int out_size, void* d_ws, size_t ws_size,
                              hipStream_t stream) {
    const float* in_embs = (const float*)d_in[0];
    const int*   rows    = (const int*)d_in[1];
    const int*   cols    = (const int*)d_in[2];
    float* out = (float*)d_out;

    const int E = in_sizes[1];
    const size_t buf_bytes = (size_t)N_NODES * D * sizeof(float);

    // workspace layout (256B aligned chunks)
    auto align256 = [](size_t x) { return (x + 255) & ~(size_t)255; };
    char* p = (char*)d_ws;
    float* bufA    = (float*)p;  p += align256(buf_bytes);
    float* bufB    = (float*)p;  p += align256(buf_bytes);
    int*   csr_col = (int*)p;    p += align256((size_t)E * sizeof(int));
    int*   row_ptr = (int*)p;    p += align256((size_t)(N_NODES + 1) * sizeof(int));
    int*   cursor  = (int*)p;    p += align256((size_t)N_NODES * sizeof(int));
    float* dinv    = (float*)p;  p += align256((size_t)N_NODES * sizeof(float));

    const int eb = (E + 255) / 256;
    const int nb = (N_NODES + 255) / 256;

    // --- CSR build ---
    hipMemsetAsync(cursor, 0, (size_t)N_NODES * sizeof(int), stream);
    hist_kernel<<<eb, 256, 0, stream>>>(rows, cursor, E);
    scan_kernel<<<1, 1024, 0, stream>>>(cursor, row_ptr, cursor, N_NODES);
    dinv_kernel<<<nb, 256, 0, stream>>>(row_ptr, dinv, N_NODES);
    scatter_kernel<<<eb, 256, 0, stream>>>(rows, cols, cursor, csr_col, E);

    // --- 3 propagation layers ---
    const int spmm_blocks = (N_NODES + 3) / 4;
    const float* xin = in_embs;
    float* xa = bufA;
    float* xb = bufB;
    for (int layer = 0; layer < 3; ++layer) {
        spmm_norm<<<spmm_blocks, 256, 0, stream>>>(
            xin, row_ptr, csr_col, dinv, in_embs, xa, out,
            1.0f / (layer + 1), layer == 0 ? 1 : 0);
        xin = xa;
        float* t = xa; xa = xb; xb = t;
    }
}

// Round 3
// 663.980 us; speedup vs baseline: 14.1798x; 2.0501x over previous
//
#include <hip/hip_runtime.h>
#include <hip/hip_bf16.h>

// LightGCN propagation on MI355X — round 3.
// Pull-CSR SpMM with cooperative column-index staging (shfl broadcast) and
// 4-deep unrolled row gathers for memory-level parallelism.
// CSR build: int4 histogram -> 3-kernel hierarchical scan (dinv fused) ->
// int4 scatter.

constexpr int N_NODES = 150000;
constexpr int D = 64;

// ---------------- CSR build ----------------

__global__ __launch_bounds__(256) void hist_kernel(
    const int* __restrict__ rows, int* __restrict__ cnt, int E)
{
    int i = (blockIdx.x * blockDim.x + threadIdx.x) * 4;
    if (i + 3 < E) {
        int4 r = *reinterpret_cast<const int4*>(rows + i);
        atomicAdd(&cnt[r.x], 1);
        atomicAdd(&cnt[r.y], 1);
        atomicAdd(&cnt[r.z], 1);
        atomicAdd(&cnt[r.w], 1);
    } else {
        for (int k = i; k < E; ++k) atomicAdd(&cnt[rows[k]], 1);
    }
}

// Per-block (1024) exclusive scan of cnt -> row_ptr (block-local), totals -> part.
__global__ __launch_bounds__(1024) void scan_block(
    const int* __restrict__ cnt, int* __restrict__ row_ptr,
    int* __restrict__ part, int n)
{
    __shared__ int wsum[16];
    const int tid = threadIdx.x, lane = tid & 63, w = tid >> 6;
    int i = blockIdx.x * 1024 + tid;
    int v = (i < n) ? cnt[i] : 0;
    int incl = v;
    #pragma unroll
    for (int off = 1; off < 64; off <<= 1) {
        int t = __shfl_up(incl, off);
        if (lane >= off) incl += t;
    }
    if (lane == 63) wsum[w] = incl;
    __syncthreads();
    int woff = 0;
    #pragma unroll
    for (int k = 0; k < 16; ++k) woff += (k < w) ? wsum[k] : 0;
    if (i < n) row_ptr[i] = woff + incl - v;       // block-local exclusive
    if (tid == 1023) part[blockIdx.x] = woff + incl; // block total
}

// Single-wave exclusive scan of the block totals; writes grand total to row_ptr[n].
__global__ __launch_bounds__(64) void scan_part(
    int* __restrict__ part, int nb, int* __restrict__ row_ptr, int n)
{
    const int lane = threadIdx.x;
    int carry = 0;
    for (int base = 0; base < nb; base += 64) {
        int i = base + lane;
        int v = (i < nb) ? part[i] : 0;
        int incl = v;
        #pragma unroll
        for (int off = 1; off < 64; off <<= 1) {
            int t = __shfl_up(incl, off);
            if (lane >= off) incl += t;
        }
        if (i < nb) part[i] = carry + incl - v;    // exclusive
        carry += __shfl(incl, 63);
    }
    if (lane == 0) row_ptr[n] = carry;
}

// row_ptr += part[block]; copy to cursor; dinv = rsqrt(deg + 1e-7).
__global__ __launch_bounds__(1024) void apply_offsets(
    int* __restrict__ row_ptr, int* __restrict__ cursor,
    float* __restrict__ dinv, const int* __restrict__ cnt,
    const int* __restrict__ part, int n)
{
    int i = blockIdx.x * 1024 + threadIdx.x;
    if (i < n) {
        int rp = row_ptr[i] + part[blockIdx.x];
        row_ptr[i] = rp;
        cursor[i] = rp;
        dinv[i] = rsqrtf((float)cnt[i] + 1e-7f);
    }
}

__global__ __launch_bounds__(256) void scatter_kernel(
    const int* __restrict__ rows, const int* __restrict__ cols,
    int* __restrict__ cursor, int* __restrict__ csr_col, int E)
{
    int i = (blockIdx.x * blockDim.x + threadIdx.x) * 4;
    if (i + 3 < E) {
        int4 r = *reinterpret_cast<const int4*>(rows + i);
        int4 c = *reinterpret_cast<const int4*>(cols + i);
        csr_col[atomicAdd(&cursor[r.x], 1)] = c.x;
        csr_col[atomicAdd(&cursor[r.y], 1)] = c.y;
        csr_col[atomicAdd(&cursor[r.z], 1)] = c.z;
        csr_col[atomicAdd(&cursor[r.w], 1)] = c.w;
    } else {
        for (int k = i; k < E; ++k)
            csr_col[atomicAdd(&cursor[rows[k]], 1)] = cols[k];
    }
}

// ---------------- fused SpMM + normalize + accumulate ----------------
// 256 threads = 4 waves = 4 rows; lane = embedding dim.
// Cols + weights staged cooperatively (1 coalesced load per 64 neighbors),
// broadcast by shfl; x-row gathers unrolled x4 for MLP.
__global__ __launch_bounds__(256) void spmm_norm(
    const float* __restrict__ x,
    const int* __restrict__ row_ptr,
    const int* __restrict__ csr_col,
    const float* __restrict__ dinv,
    const float* __restrict__ init,
    float* __restrict__ xnew,
    float* __restrict__ out,
    float invl, int first)
{
    int row = blockIdx.x * 4 + (threadIdx.x >> 6);
    if (row >= N_NODES) return;
    int lane = threadIdx.x & 63;

    int beg = row_ptr[row];
    int end = row_ptr[row + 1];
    float dr = dinv[row];

    float acc = 0.f;
    for (int base = beg; base < end; base += 64) {
        int nchunk = min(64, end - base);
        int li = base + lane;
        int c_l = 0;
        float w_l = 0.f;
        if (li < end) {
            c_l = csr_col[li];
            w_l = dinv[c_l];
        }
        int j = 0;
        for (; j + 4 <= nchunk; j += 4) {
            int   c0 = __shfl(c_l, j + 0);
            int   c1 = __shfl(c_l, j + 1);
            int   c2 = __shfl(c_l, j + 2);
            int   c3 = __shfl(c_l, j + 3);
            float w0 = __shfl(w_l, j + 0);
            float w1 = __shfl(w_l, j + 1);
            float w2 = __shfl(w_l, j + 2);
            float w3 = __shfl(w_l, j + 3);
            float x0 = x[(size_t)c0 * D + lane];
            float x1 = x[(size_t)c1 * D + lane];
            float x2 = x[(size_t)c2 * D + lane];
            float x3 = x[(size_t)c3 * D + lane];
            acc += w0 * x0;
            acc += w1 * x1;
            acc += w2 * x2;
            acc += w3 * x3;
        }
        for (; j < nchunk; ++j) {
            int   c = __shfl(c_l, j);
            float w = __shfl(w_l, j);
            acc += w * x[(size_t)c * D + lane];
        }
    }
    acc *= dr;

    float ss = acc * acc;
    #pragma unroll
    for (int off = 32; off > 0; off >>= 1)
        ss += __shfl_xor(ss, off);
    float nrm = sqrtf(ss);
    float xn = acc / fmaxf(nrm, 1e-12f);

    size_t idx = (size_t)row * D + lane;
    xnew[idx] = xn;
    out[idx] = (first ? init[idx] : out[idx]) + xn * invl;
}

extern "C" void kernel_launch(void* const* d_in, const int* in_sizes, int n_in,
                              void* d_out, int out_size, void* d_ws, size_t ws_size,
                              hipStream_t stream) {
    const float* in_embs = (const float*)d_in[0];
    const int*   rows    = (const int*)d_in[1];
    const int*   cols    = (const int*)d_in[2];
    float* out = (float*)d_out;

    const int E = in_sizes[1];
    const size_t buf_bytes = (size_t)N_NODES * D * sizeof(float);

    auto align256 = [](size_t x) { return (x + 255) & ~(size_t)255; };
    char* p = (char*)d_ws;
    float* bufA    = (float*)p;  p += align256(buf_bytes);
    float* bufB    = (float*)p;  p += align256(buf_bytes);
    int*   csr_col = (int*)p;    p += align256((size_t)E * sizeof(int));
    int*   row_ptr = (int*)p;    p += align256((size_t)(N_NODES + 1) * sizeof(int));
    int*   cursor  = (int*)p;    p += align256((size_t)N_NODES * sizeof(int));
    int*   cnt     = (int*)p;    p += align256((size_t)N_NODES * sizeof(int));
    float* dinv    = (float*)p;  p += align256((size_t)N_NODES * sizeof(float));
    int*   part    = (int*)p;    p += align256(1024 * sizeof(int));

    const int eb4 = (E / 4 + 255) / 256 + 1;          // threads handle 4 edges each
    const int nb1024 = (N_NODES + 1023) / 1024;       // 147 blocks

    // --- CSR build ---
    hipMemsetAsync(cnt, 0, (size_t)N_NODES * sizeof(int), stream);
    hist_kernel<<<eb4, 256, 0, stream>>>(rows, cnt, E);
    scan_block<<<nb1024, 1024, 0, stream>>>(cnt, row_ptr, part, N_NODES);
    scan_part<<<1, 64, 0, stream>>>(part, nb1024, row_ptr, N_NODES);
    apply_offsets<<<nb1024, 1024, 0, stream>>>(row_ptr, cursor, dinv, cnt, part, N_NODES);
    scatter_kernel<<<eb4, 256, 0, stream>>>(rows, cols, cursor, csr_col, E);

    // --- 3 propagation layers ---
    const int spmm_blocks = (N_NODES + 3) / 4;
    const float* xin = in_embs;
    float* xa = bufA;
    float* xb = bufB;
    for (int layer = 0; layer < 3; ++layer) {
        spmm_norm<<<spmm_blocks, 256, 0, stream>>>(
            xin, row_ptr, csr_col, dinv, in_embs, xa, out,
            1.0f / (layer + 1), layer == 0 ? 1 : 0);
        xin = xa;
        float* t = xa; xa = xb; xb = t;
    }
}

// Round 4
// 579.187 us; speedup vs baseline: 16.2557x; 1.1464x over previous
//
#include <hip/hip_runtime.h>
#include <hip/hip_bf16.h>

// LightGCN on MI355X — round 4.
// Key structural insight: edges arrive sorted by (u,v) with
//   rows = [u, v+N_USERS], cols = [v+N_USERS, u].
// => first half of (rows, cols) IS the user-CSR (rows sorted). Zero build.
//    row_ptr_users via binary search over sorted rows[0:E/2].
// => only the item half needs hist + scan + atomic scatter (E/2 edges).
// SpMM: 16-lane groups (4 rows/wave), float4 lanes, x4 unrolled gathers.

constexpr int N_USERS = 100000;
constexpr int N_ITEMS = 50000;
constexpr int N_NODES = N_USERS + N_ITEMS;
constexpr int D = 64;

// ---- user row_ptr: lower_bound over sorted rows[0:Eh] ----
__global__ __launch_bounds__(256) void rpu_kernel(
    const int* __restrict__ rows, int* __restrict__ rpu, int Eh)
{
    int i = blockIdx.x * 256 + threadIdx.x;
    if (i > N_USERS) return;
    int lo = 0, hi = Eh;
    while (lo < hi) {
        int mid = (lo + hi) >> 1;
        if (rows[mid] < i) lo = mid + 1; else hi = mid;
    }
    rpu[i] = lo;
}

// ---- item histogram (filtered full scan keeps int4 alignment) ----
__global__ __launch_bounds__(256) void hist_items(
    const int* __restrict__ rows, int* __restrict__ cnt, int E)
{
    int i = (blockIdx.x * blockDim.x + threadIdx.x) * 4;
    if (i + 3 < E) {
        int4 r = *reinterpret_cast<const int4*>(rows + i);
        if (r.x >= N_USERS) atomicAdd(&cnt[r.x - N_USERS], 1);
        if (r.y >= N_USERS) atomicAdd(&cnt[r.y - N_USERS], 1);
        if (r.z >= N_USERS) atomicAdd(&cnt[r.z - N_USERS], 1);
        if (r.w >= N_USERS) atomicAdd(&cnt[r.w - N_USERS], 1);
    } else {
        for (int k = i; k < E; ++k) {
            int r = rows[k];
            if (r >= N_USERS) atomicAdd(&cnt[r - N_USERS], 1);
        }
    }
}

// ---- hierarchical scan over N_ITEMS ----
__global__ __launch_bounds__(1024) void scan_block(
    const int* __restrict__ cnt, int* __restrict__ rp,
    int* __restrict__ part, int n)
{
    __shared__ int wsum[16];
    const int tid = threadIdx.x, lane = tid & 63, w = tid >> 6;
    int i = blockIdx.x * 1024 + tid;
    int v = (i < n) ? cnt[i] : 0;
    int incl = v;
    #pragma unroll
    for (int off = 1; off < 64; off <<= 1) {
        int t = __shfl_up(incl, off);
        if (lane >= off) incl += t;
    }
    if (lane == 63) wsum[w] = incl;
    __syncthreads();
    int woff = 0;
    #pragma unroll
    for (int k = 0; k < 16; ++k) woff += (k < w) ? wsum[k] : 0;
    if (i < n) rp[i] = woff + incl - v;
    if (tid == 1023) part[blockIdx.x] = woff + incl;
}

__global__ __launch_bounds__(64) void scan_part(
    int* __restrict__ part, int nb, int* __restrict__ rp, int n)
{
    const int lane = threadIdx.x;
    int carry = 0;
    for (int base = 0; base < nb; base += 64) {
        int i = base + lane;
        int v = (i < nb) ? part[i] : 0;
        int incl = v;
        #pragma unroll
        for (int off = 1; off < 64; off <<= 1) {
            int t = __shfl_up(incl, off);
            if (lane >= off) incl += t;
        }
        if (i < nb) part[i] = carry + incl - v;
        carry += __shfl(incl, 63);
    }
    if (lane == 0) rp[n] = carry;
}

__global__ __launch_bounds__(1024) void apply_offsets(
    int* __restrict__ rp, int* __restrict__ cursor,
    const int* __restrict__ part, int n)
{
    int i = blockIdx.x * 1024 + threadIdx.x;
    if (i < n) {
        int v = rp[i] + part[blockIdx.x];
        rp[i] = v;
        cursor[i] = v;
    }
}

// ---- dinv for all nodes ----
__global__ __launch_bounds__(256) void dinv_all(
    const int* __restrict__ rpu, const int* __restrict__ cnt_i,
    float* __restrict__ dinv, int n)
{
    int i = blockIdx.x * 256 + threadIdx.x;
    if (i < n) {
        float deg = (i < N_USERS) ? (float)(rpu[i + 1] - rpu[i])
                                  : (float)cnt_i[i - N_USERS];
        dinv[i] = rsqrtf(deg + 1e-7f);
    }
}

// ---- item scatter (filtered full scan) ----
__global__ __launch_bounds__(256) void scatter_items(
    const int* __restrict__ rows, const int* __restrict__ cols,
    int* __restrict__ cursor, int* __restrict__ csr_col_i, int E)
{
    int i = (blockIdx.x * blockDim.x + threadIdx.x) * 4;
    if (i + 3 < E) {
        int4 r = *reinterpret_cast<const int4*>(rows + i);
        int4 c = *reinterpret_cast<const int4*>(cols + i);
        if (r.x >= N_USERS) csr_col_i[atomicAdd(&cursor[r.x - N_USERS], 1)] = c.x;
        if (r.y >= N_USERS) csr_col_i[atomicAdd(&cursor[r.y - N_USERS], 1)] = c.y;
        if (r.z >= N_USERS) csr_col_i[atomicAdd(&cursor[r.z - N_USERS], 1)] = c.z;
        if (r.w >= N_USERS) csr_col_i[atomicAdd(&cursor[r.w - N_USERS], 1)] = c.w;
    } else {
        for (int k = i; k < E; ++k) {
            int r = rows[k];
            if (r >= N_USERS) csr_col_i[atomicAdd(&cursor[r - N_USERS], 1)] = cols[k];
        }
    }
}

// ---- fused SpMM + L2-normalize + out accumulate ----
// 256 threads = 4 waves; wave = 4 rows via 16-lane groups; float4 per lane.
__global__ __launch_bounds__(256) void spmm_norm(
    const float* __restrict__ x,
    const int* __restrict__ rpu,
    const int* __restrict__ rpi,
    const int* __restrict__ cols_u,      // = cols (first half): item global ids
    const int* __restrict__ csr_col_i,   // user global ids
    const float* __restrict__ dinv,
    const float* __restrict__ init,
    float* __restrict__ xnew,
    float* __restrict__ out,
    float invl, int first)
{
    const int tid = threadIdx.x;
    const int lane = tid & 63;
    const int g = lane >> 4;         // group 0..3 within wave
    const int sl = lane & 15;        // sub-lane: owns float4 at sl*4
    const int wave = tid >> 6;
    const int row = blockIdx.x * 16 + wave * 4 + g;
    if (row >= N_NODES) return;
    const int gb = g << 4;

    int beg, end;
    const int* clist;
    if (row < N_USERS) {
        beg = rpu[row]; end = rpu[row + 1]; clist = cols_u;
    } else {
        int v = row - N_USERS;
        beg = rpi[v]; end = rpi[v + 1]; clist = csr_col_i;
    }
    float dr = dinv[row];

    float ax = 0.f, ay = 0.f, az = 0.f, aw = 0.f;
    for (int base = beg; base < end; base += 16) {
        int li = base + sl;
        int c_l = 0; float w_l = 0.f;
        if (li < end) { c_l = clist[li]; w_l = dinv[c_l]; }
        int nch = min(16, end - base);
        int j = 0;
        for (; j + 4 <= nch; j += 4) {
            int   c0 = __shfl(c_l, gb + j + 0);
            int   c1 = __shfl(c_l, gb + j + 1);
            int   c2 = __shfl(c_l, gb + j + 2);
            int   c3 = __shfl(c_l, gb + j + 3);
            float w0 = __shfl(w_l, gb + j + 0);
            float w1 = __shfl(w_l, gb + j + 1);
            float w2 = __shfl(w_l, gb + j + 2);
            float w3 = __shfl(w_l, gb + j + 3);
            float4 x0 = *reinterpret_cast<const float4*>(x + (size_t)c0 * D + sl * 4);
            float4 x1 = *reinterpret_cast<const float4*>(x + (size_t)c1 * D + sl * 4);
            float4 x2 = *reinterpret_cast<const float4*>(x + (size_t)c2 * D + sl * 4);
            float4 x3 = *reinterpret_cast<const float4*>(x + (size_t)c3 * D + sl * 4);
            ax += w0 * x0.x; ay += w0 * x0.y; az += w0 * x0.z; aw += w0 * x0.w;
            ax += w1 * x1.x; ay += w1 * x1.y; az += w1 * x1.z; aw += w1 * x1.w;
            ax += w2 * x2.x; ay += w2 * x2.y; az += w2 * x2.z; aw += w2 * x2.w;
            ax += w3 * x3.x; ay += w3 * x3.y; az += w3 * x3.z; aw += w3 * x3.w;
        }
        for (; j < nch; ++j) {
            int   c = __shfl(c_l, gb + j);
            float w = __shfl(w_l, gb + j);
            float4 xv = *reinterpret_cast<const float4*>(x + (size_t)c * D + sl * 4);
            ax += w * xv.x; ay += w * xv.y; az += w * xv.z; aw += w * xv.w;
        }
    }
    ax *= dr; ay *= dr; az *= dr; aw *= dr;

    float ss = ax * ax + ay * ay + az * az + aw * aw;
    #pragma unroll
    for (int off = 8; off > 0; off >>= 1)
        ss += __shfl_xor(ss, off);
    float nrm = sqrtf(ss);
    float rinv = 1.0f / fmaxf(nrm, 1e-12f);

    float4 xn;
    xn.x = ax * rinv; xn.y = ay * rinv; xn.z = az * rinv; xn.w = aw * rinv;

    size_t idx = (size_t)row * D + sl * 4;
    *reinterpret_cast<float4*>(xnew + idx) = xn;

    float4 b = first ? *reinterpret_cast<const float4*>(init + idx)
                     : *reinterpret_cast<const float4*>(out + idx);
    b.x += xn.x * invl; b.y += xn.y * invl; b.z += xn.z * invl; b.w += xn.w * invl;
    *reinterpret_cast<float4*>(out + idx) = b;
}

extern "C" void kernel_launch(void* const* d_in, const int* in_sizes, int n_in,
                              void* d_out, int out_size, void* d_ws, size_t ws_size,
                              hipStream_t stream) {
    const float* in_embs = (const float*)d_in[0];
    const int*   rows    = (const int*)d_in[1];
    const int*   cols    = (const int*)d_in[2];
    float* out = (float*)d_out;

    const int E = in_sizes[1];
    const int Eh = E / 2;
    const size_t buf_bytes = (size_t)N_NODES * D * sizeof(float);

    auto align256 = [](size_t x) { return (x + 255) & ~(size_t)255; };
    char* p = (char*)d_ws;
    float* bufA      = (float*)p; p += align256(buf_bytes);
    float* bufB      = (float*)p; p += align256(buf_bytes);
    int*   csr_col_i = (int*)p;   p += align256((size_t)Eh * sizeof(int));
    int*   rpu       = (int*)p;   p += align256((size_t)(N_USERS + 1) * sizeof(int));
    int*   rpi       = (int*)p;   p += align256((size_t)(N_ITEMS + 1) * sizeof(int));
    int*   cursor    = (int*)p;   p += align256((size_t)N_ITEMS * sizeof(int));
    int*   cnt_i     = (int*)p;   p += align256((size_t)N_ITEMS * sizeof(int));
    float* dinv      = (float*)p; p += align256((size_t)N_NODES * sizeof(float));
    int*   part      = (int*)p;   p += align256(1024 * sizeof(int));

    const int eb4 = (E / 4 + 255) / 256 + 1;
    const int nbi = (N_ITEMS + 1023) / 1024;   // 49

    // --- CSR build (items only; user CSR is free) ---
    hipMemsetAsync(cnt_i, 0, (size_t)N_ITEMS * sizeof(int), stream);
    hist_items<<<eb4, 256, 0, stream>>>(rows, cnt_i, E);
    rpu_kernel<<<(N_USERS + 256) / 256, 256, 0, stream>>>(rows, rpu, Eh);
    scan_block<<<nbi, 1024, 0, stream>>>(cnt_i, rpi, part, N_ITEMS);
    scan_part<<<1, 64, 0, stream>>>(part, nbi, rpi, N_ITEMS);
    apply_offsets<<<nbi, 1024, 0, stream>>>(rpi, cursor, part, N_ITEMS);
    dinv_all<<<(N_NODES + 255) / 256, 256, 0, stream>>>(rpu, cnt_i, dinv, N_NODES);
    scatter_items<<<eb4, 256, 0, stream>>>(rows, cols, cursor, csr_col_i, E);

    // --- 3 propagation layers ---
    const int spmm_blocks = (N_NODES + 15) / 16;
    const float* xin = in_embs;
    float* xa = bufA;
    float* xb = bufB;
    for (int layer = 0; layer < 3; ++layer) {
        spmm_norm<<<spmm_blocks, 256, 0, stream>>>(
            xin, rpu, rpi, cols, csr_col_i, dinv, in_embs, xa, out,
            1.0f / (layer + 1), layer == 0 ? 1 : 0);
        xin = xa;
        float* t = xa; xa = xb; xb = t;
    }
}

// Round 5
// 399.821 us; speedup vs baseline: 23.5483x; 1.4486x over previous
//
#include <hip/hip_runtime.h>
#include <hip/hip_bf16.h>

// LightGCN on MI355X — round 5.
// User CSR is free (edge list sorted by u). Item CSR via two-pass bucket
// counting sort: block-local LDS histograms + per-(block,bucket) global
// reservation -> line-dense staging writes; per-bucket LDS sort -> final CSR,
// rpi and item dinv emitted in-pass. No 1.6M-way global atomics anywhere.

constexpr int N_USERS = 100000;
constexpr int N_ITEMS = 50000;
constexpr int N_NODES = N_USERS + N_ITEMS;
constexpr int D = 64;
constexpr int NBK  = 196;     // item buckets: bucket = v >> 8 (256 items each)
constexpr int SLOT = 12288;   // staging slot per bucket (mean ~8160, 40+ sigma)
constexpr int EPB  = 16384;   // edges per block in bucket_scatter

// ---- user row_ptr: lower_bound over sorted rows[0:Eh] ----
__global__ __launch_bounds__(256) void rpu_kernel(
    const int* __restrict__ rows, int* __restrict__ rpu, int Eh)
{
    int i = blockIdx.x * 256 + threadIdx.x;
    if (i > N_USERS) return;
    int lo = 0, hi = Eh;
    while (lo < hi) {
        int mid = (lo + hi) >> 1;
        if (rows[mid] < i) lo = mid + 1; else hi = mid;
    }
    rpu[i] = lo;
}

__global__ __launch_bounds__(256) void dinv_users(
    const int* __restrict__ rpu, float* __restrict__ dinv)
{
    int i = blockIdx.x * 256 + threadIdx.x;
    if (i < N_USERS)
        dinv[i] = rsqrtf((float)(rpu[i + 1] - rpu[i]) + 1e-7f);
}

__global__ __launch_bounds__(256) void init_cursors(int* __restrict__ bcur)
{
    int t = threadIdx.x;
    if (t < NBK) bcur[t] = t * SLOT;
}

// ---- pass 1: bucket scatter of (u, vlocal) from the first edge half ----
// first half: rows[i] = u (sorted), cols[i] = v + N_USERS.
__global__ __launch_bounds__(256) void bucket_scatter(
    const int* __restrict__ rows, const int* __restrict__ cols,
    int* __restrict__ bcur, int* __restrict__ staging, int Eh)
{
    __shared__ int hist[256];   // bucket counts, then global write cursors
    const int tid = threadIdx.x;
    const int base = blockIdx.x * EPB;
    const int nEdge = min(EPB, Eh - base);
    if (nEdge <= 0) return;

    hist[tid] = 0;
    __syncthreads();

    // phase A: LDS histogram over buckets (cols only)
    for (int s = 0; s < 16; ++s) {
        int o = s * 1024 + tid * 4;
        if (o + 3 < nEdge) {
            int4 c4 = *reinterpret_cast<const int4*>(cols + base + o);
            atomicAdd(&hist[(c4.x - N_USERS) >> 8], 1);
            atomicAdd(&hist[(c4.y - N_USERS) >> 8], 1);
            atomicAdd(&hist[(c4.z - N_USERS) >> 8], 1);
            atomicAdd(&hist[(c4.w - N_USERS) >> 8], 1);
        } else if (o < nEdge) {
            for (int k = o; k < nEdge; ++k)
                atomicAdd(&hist[(cols[base + k] - N_USERS) >> 8], 1);
        }
    }
    __syncthreads();

    // phase B: reserve global space per (block, bucket); hist becomes cursor
    if (tid < NBK) {
        int h = hist[tid];
        hist[tid] = (h > 0) ? atomicAdd(&bcur[tid], h) : 0;
    }
    __syncthreads();

    // phase C: scatter packed entries (vlocal<<24 | u) into reserved runs
    for (int s = 0; s < 16; ++s) {
        int o = s * 1024 + tid * 4;
        if (o + 3 < nEdge) {
            int4 c4 = *reinterpret_cast<const int4*>(cols + base + o);
            int4 u4 = *reinterpret_cast<const int4*>(rows + base + o);
            int v, p;
            v = c4.x - N_USERS; p = atomicAdd(&hist[v >> 8], 1);
            staging[p] = ((v & 255) << 24) | u4.x;
            v = c4.y - N_USERS; p = atomicAdd(&hist[v >> 8], 1);
            staging[p] = ((v & 255) << 24) | u4.y;
            v = c4.z - N_USERS; p = atomicAdd(&hist[v >> 8], 1);
            staging[p] = ((v & 255) << 24) | u4.z;
            v = c4.w - N_USERS; p = atomicAdd(&hist[v >> 8], 1);
            staging[p] = ((v & 255) << 24) | u4.w;
        } else if (o < nEdge) {
            for (int k = o; k < nEdge; ++k) {
                int v = cols[base + k] - N_USERS;
                int u = rows[base + k];
                int p = atomicAdd(&hist[v >> 8], 1);
                staging[p] = ((v & 255) << 24) | u;
            }
        }
    }
}

// ---- exclusive scan of 196 bucket totals -> bucket CSR bases ----
__global__ __launch_bounds__(256) void scan_buckets(
    const int* __restrict__ bcur, int* __restrict__ bbase, int* __restrict__ rpi)
{
    __shared__ int wsum[4];
    const int tid = threadIdx.x, lane = tid & 63, w = tid >> 6;
    int t = (tid < NBK) ? (bcur[tid] - tid * SLOT) : 0;
    int incl = t;
    #pragma unroll
    for (int off = 1; off < 64; off <<= 1) {
        int s = __shfl_up(incl, off);
        if (lane >= off) incl += s;
    }
    if (lane == 63) wsum[w] = incl;
    __syncthreads();
    int woff = 0;
    #pragma unroll
    for (int k = 0; k < 4; ++k) woff += (k < w) ? wsum[k] : 0;
    int excl = woff + incl - t;
    if (tid < NBK) bbase[tid] = excl;
    if (tid == NBK - 1) rpi[N_ITEMS] = excl + t;
}

// ---- pass 2: per-bucket sort -> final item CSR + rpi + item dinv ----
__global__ __launch_bounds__(256) void item_csr(
    const int* __restrict__ bcur, const int* __restrict__ bbase,
    const int* __restrict__ staging, int* __restrict__ rpi,
    float* __restrict__ dinv, int* __restrict__ csr)
{
    __shared__ int hist[256];
    __shared__ int cur[256];
    __shared__ int wsum[4];
    const int b = blockIdx.x;
    const int tid = threadIdx.x, lane = tid & 63, w = tid >> 6;
    const int sbase = b * SLOT;
    const int n = bcur[b] - sbase;
    const int cbase = bbase[b];

    hist[tid] = 0;
    __syncthreads();
    for (int i = tid; i < n; i += 256)
        atomicAdd(&hist[((unsigned)staging[sbase + i]) >> 24], 1);
    __syncthreads();

    int h = hist[tid];
    int incl = h;
    #pragma unroll
    for (int off = 1; off < 64; off <<= 1) {
        int s = __shfl_up(incl, off);
        if (lane >= off) incl += s;
    }
    if (lane == 63) wsum[w] = incl;
    __syncthreads();
    int woff = 0;
    #pragma unroll
    for (int k = 0; k < 4; ++k) woff += (k < w) ? wsum[k] : 0;
    int excl = woff + incl - h;

    int gitem = b * 256 + tid;
    if (gitem < N_ITEMS) {
        rpi[gitem] = cbase + excl;
        dinv[N_USERS + gitem] = rsqrtf((float)h + 1e-7f);
    }
    cur[tid] = cbase + excl;
    __syncthreads();

    for (int i = tid; i < n; i += 256) {
        int e = staging[sbase + i];
        int p = atomicAdd(&cur[((unsigned)e) >> 24], 1);
        csr[p] = e & 0xFFFFFF;
    }
}

// ---- fused SpMM + L2-normalize + out accumulate ----
// 256 threads = 4 waves; wave = 4 rows via 16-lane groups; float4 per lane.
__global__ __launch_bounds__(256) void spmm_norm(
    const float* __restrict__ x,
    const int* __restrict__ rpu,
    const int* __restrict__ rpi,
    const int* __restrict__ cols_u,
    const int* __restrict__ csr_col_i,
    const float* __restrict__ dinv,
    const float* __restrict__ init,
    float* __restrict__ xnew,
    float* __restrict__ out,
    float invl, int first)
{
    const int tid = threadIdx.x;
    const int lane = tid & 63;
    const int g = lane >> 4;
    const int sl = lane & 15;
    const int wave = tid >> 6;
    const int row = blockIdx.x * 16 + wave * 4 + g;
    if (row >= N_NODES) return;
    const int gb = g << 4;

    int beg, end;
    const int* clist;
    if (row < N_USERS) {
        beg = rpu[row]; end = rpu[row + 1]; clist = cols_u;
    } else {
        int v = row - N_USERS;
        beg = rpi[v]; end = rpi[v + 1]; clist = csr_col_i;
    }
    float dr = dinv[row];

    float ax = 0.f, ay = 0.f, az = 0.f, aw = 0.f;
    for (int base = beg; base < end; base += 16) {
        int li = base + sl;
        int c_l = 0; float w_l = 0.f;
        if (li < end) { c_l = clist[li]; w_l = dinv[c_l]; }
        int nch = min(16, end - base);
        int j = 0;
        for (; j + 4 <= nch; j += 4) {
            int   c0 = __shfl(c_l, gb + j + 0);
            int   c1 = __shfl(c_l, gb + j + 1);
            int   c2 = __shfl(c_l, gb + j + 2);
            int   c3 = __shfl(c_l, gb + j + 3);
            float w0 = __shfl(w_l, gb + j + 0);
            float w1 = __shfl(w_l, gb + j + 1);
            float w2 = __shfl(w_l, gb + j + 2);
            float w3 = __shfl(w_l, gb + j + 3);
            float4 x0 = *reinterpret_cast<const float4*>(x + (size_t)c0 * D + sl * 4);
            float4 x1 = *reinterpret_cast<const float4*>(x + (size_t)c1 * D + sl * 4);
            float4 x2 = *reinterpret_cast<const float4*>(x + (size_t)c2 * D + sl * 4);
            float4 x3 = *reinterpret_cast<const float4*>(x + (size_t)c3 * D + sl * 4);
            ax += w0 * x0.x; ay += w0 * x0.y; az += w0 * x0.z; aw += w0 * x0.w;
            ax += w1 * x1.x; ay += w1 * x1.y; az += w1 * x1.z; aw += w1 * x1.w;
            ax += w2 * x2.x; ay += w2 * x2.y; az += w2 * x2.z; aw += w2 * x2.w;
            ax += w3 * x3.x; ay += w3 * x3.y; az += w3 * x3.z; aw += w3 * x3.w;
        }
        for (; j < nch; ++j) {
            int   c = __shfl(c_l, gb + j);
            float w = __shfl(w_l, gb + j);
            float4 xv = *reinterpret_cast<const float4*>(x + (size_t)c * D + sl * 4);
            ax += w * xv.x; ay += w * xv.y; az += w * xv.z; aw += w * xv.w;
        }
    }
    ax *= dr; ay *= dr; az *= dr; aw *= dr;

    float ss = ax * ax + ay * ay + az * az + aw * aw;
    #pragma unroll
    for (int off = 8; off > 0; off >>= 1)
        ss += __shfl_xor(ss, off);
    float nrm = sqrtf(ss);
    float rinv = 1.0f / fmaxf(nrm, 1e-12f);

    float4 xn;
    xn.x = ax * rinv; xn.y = ay * rinv; xn.z = az * rinv; xn.w = aw * rinv;

    size_t idx = (size_t)row * D + sl * 4;
    *reinterpret_cast<float4*>(xnew + idx) = xn;

    float4 bo = first ? *reinterpret_cast<const float4*>(init + idx)
                      : *reinterpret_cast<const float4*>(out + idx);
    bo.x += xn.x * invl; bo.y += xn.y * invl; bo.z += xn.z * invl; bo.w += xn.w * invl;
    *reinterpret_cast<float4*>(out + idx) = bo;
}

extern "C" void kernel_launch(void* const* d_in, const int* in_sizes, int n_in,
                              void* d_out, int out_size, void* d_ws, size_t ws_size,
                              hipStream_t stream) {
    const float* in_embs = (const float*)d_in[0];
    const int*   rows    = (const int*)d_in[1];
    const int*   cols    = (const int*)d_in[2];
    float* out = (float*)d_out;

    const int E  = in_sizes[1];
    const int Eh = E / 2;
    const size_t buf_bytes = (size_t)N_NODES * D * sizeof(float);

    auto align256 = [](size_t x) { return (x + 255) & ~(size_t)255; };
    char* p = (char*)d_ws;
    float* bufA      = (float*)p; p += align256(buf_bytes);
    float* bufB      = (float*)p; p += align256(buf_bytes);
    int*   csr_col_i = (int*)p;   p += align256((size_t)Eh * sizeof(int));
    int*   rpu       = (int*)p;   p += align256((size_t)(N_USERS + 1) * sizeof(int));
    int*   rpi       = (int*)p;   p += align256((size_t)(N_ITEMS + 1) * sizeof(int));
    float* dinv      = (float*)p; p += align256((size_t)N_NODES * sizeof(float));
    int*   bcur      = (int*)p;   p += align256(256 * sizeof(int));
    int*   bbase     = (int*)p;   p += align256(256 * sizeof(int));
    // staging aliases bufB: dead until spmm layer 1, consumed by item_csr first
    int*   staging   = (int*)bufB;  // NBK*SLOT*4 = 9.6 MB < 38.4 MB

    // --- CSR build ---
    init_cursors<<<1, 256, 0, stream>>>(bcur);
    bucket_scatter<<<(Eh + EPB - 1) / EPB, 256, 0, stream>>>(rows, cols, bcur, staging, Eh);
    scan_buckets<<<1, 256, 0, stream>>>(bcur, bbase, rpi);
    item_csr<<<NBK, 256, 0, stream>>>(bcur, bbase, staging, rpi, dinv, csr_col_i);
    rpu_kernel<<<(N_USERS + 256) / 256, 256, 0, stream>>>(rows, rpu, Eh);
    dinv_users<<<(N_USERS + 255) / 256, 256, 0, stream>>>(rpu, dinv);

    // --- 3 propagation layers ---
    const int spmm_blocks = (N_NODES + 15) / 16;
    const float* xin = in_embs;
    float* xa = bufA;
    float* xb = bufB;
    for (int layer = 0; layer < 3; ++layer) {
        spmm_norm<<<spmm_blocks, 256, 0, stream>>>(
            xin, rpu, rpi, cols, csr_col_i, dinv, in_embs, xa, out,
            1.0f / (layer + 1), layer == 0 ? 1 : 0);
        xin = xa;
        float* t = xa; xa = xb; xb = t;
    }
}

// Round 6
// 250.721 us; speedup vs baseline: 37.5521x; 1.5947x over previous
//
#include <hip/hip_runtime.h>
#include <hip/hip_bf16.h>

// LightGCN on MI355X — round 6.
// Algebraic fold: normalize(dinv[r]*sum(dinv[c]x[c])) = normalize(sum(z[c]))
// with z[c] = dinv[c]*x_norm[c]. Inner loop = pure gather-sum of bf16 rows
// (128 B/row), no per-edge weights. Last layer skips the z write.
// CSR build: user side free (sorted); item side via LDS bucket counting sort.

constexpr int N_USERS = 100000;
constexpr int N_ITEMS = 50000;
constexpr int N_NODES = N_USERS + N_ITEMS;
constexpr int D = 64;
constexpr int NBK  = 196;
constexpr int SLOT = 12288;
constexpr int EPB  = 16384;

__device__ inline unsigned short f2bf(float f) {
    unsigned u = __float_as_uint(f);
    u += 0x7FFFu + ((u >> 16) & 1u);   // RNE
    return (unsigned short)(u >> 16);
}
__device__ inline float bf2f(unsigned short h) {
    return __uint_as_float((unsigned)h << 16);
}

// ---- user row_ptr: lower_bound over sorted rows[0:Eh] ----
__global__ __launch_bounds__(256) void rpu_kernel(
    const int* __restrict__ rows, int* __restrict__ rpu, int Eh)
{
    int i = blockIdx.x * 256 + threadIdx.x;
    if (i > N_USERS) return;
    int lo = 0, hi = Eh;
    while (lo < hi) {
        int mid = (lo + hi) >> 1;
        if (rows[mid] < i) lo = mid + 1; else hi = mid;
    }
    rpu[i] = lo;
}

__global__ __launch_bounds__(256) void dinv_users(
    const int* __restrict__ rpu, float* __restrict__ dinv)
{
    int i = blockIdx.x * 256 + threadIdx.x;
    if (i < N_USERS)
        dinv[i] = rsqrtf((float)(rpu[i + 1] - rpu[i]) + 1e-7f);
}

__global__ __launch_bounds__(256) void init_cursors(int* __restrict__ bcur)
{
    int t = threadIdx.x;
    if (t < NBK) bcur[t] = t * SLOT;
}

// ---- pass 1: bucket scatter of (u, vlocal) from the first edge half ----
__global__ __launch_bounds__(256) void bucket_scatter(
    const int* __restrict__ rows, const int* __restrict__ cols,
    int* __restrict__ bcur, int* __restrict__ staging, int Eh)
{
    __shared__ int hist[256];
    const int tid = threadIdx.x;
    const int base = blockIdx.x * EPB;
    const int nEdge = min(EPB, Eh - base);
    if (nEdge <= 0) return;

    hist[tid] = 0;
    __syncthreads();

    for (int s = 0; s < 16; ++s) {
        int o = s * 1024 + tid * 4;
        if (o + 3 < nEdge) {
            int4 c4 = *reinterpret_cast<const int4*>(cols + base + o);
            atomicAdd(&hist[(c4.x - N_USERS) >> 8], 1);
            atomicAdd(&hist[(c4.y - N_USERS) >> 8], 1);
            atomicAdd(&hist[(c4.z - N_USERS) >> 8], 1);
            atomicAdd(&hist[(c4.w - N_USERS) >> 8], 1);
        } else if (o < nEdge) {
            for (int k = o; k < nEdge; ++k)
                atomicAdd(&hist[(cols[base + k] - N_USERS) >> 8], 1);
        }
    }
    __syncthreads();

    if (tid < NBK) {
        int h = hist[tid];
        hist[tid] = (h > 0) ? atomicAdd(&bcur[tid], h) : 0;
    }
    __syncthreads();

    for (int s = 0; s < 16; ++s) {
        int o = s * 1024 + tid * 4;
        if (o + 3 < nEdge) {
            int4 c4 = *reinterpret_cast<const int4*>(cols + base + o);
            int4 u4 = *reinterpret_cast<const int4*>(rows + base + o);
            int v, p;
            v = c4.x - N_USERS; p = atomicAdd(&hist[v >> 8], 1);
            staging[p] = ((v & 255) << 24) | u4.x;
            v = c4.y - N_USERS; p = atomicAdd(&hist[v >> 8], 1);
            staging[p] = ((v & 255) << 24) | u4.y;
            v = c4.z - N_USERS; p = atomicAdd(&hist[v >> 8], 1);
            staging[p] = ((v & 255) << 24) | u4.z;
            v = c4.w - N_USERS; p = atomicAdd(&hist[v >> 8], 1);
            staging[p] = ((v & 255) << 24) | u4.w;
        } else if (o < nEdge) {
            for (int k = o; k < nEdge; ++k) {
                int v = cols[base + k] - N_USERS;
                int u = rows[base + k];
                int p = atomicAdd(&hist[v >> 8], 1);
                staging[p] = ((v & 255) << 24) | u;
            }
        }
    }
}

__global__ __launch_bounds__(256) void scan_buckets(
    const int* __restrict__ bcur, int* __restrict__ bbase, int* __restrict__ rpi)
{
    __shared__ int wsum[4];
    const int tid = threadIdx.x, lane = tid & 63, w = tid >> 6;
    int t = (tid < NBK) ? (bcur[tid] - tid * SLOT) : 0;
    int incl = t;
    #pragma unroll
    for (int off = 1; off < 64; off <<= 1) {
        int s = __shfl_up(incl, off);
        if (lane >= off) incl += s;
    }
    if (lane == 63) wsum[w] = incl;
    __syncthreads();
    int woff = 0;
    #pragma unroll
    for (int k = 0; k < 4; ++k) woff += (k < w) ? wsum[k] : 0;
    int excl = woff + incl - t;
    if (tid < NBK) bbase[tid] = excl;
    if (tid == NBK - 1) rpi[N_ITEMS] = excl + t;
}

__global__ __launch_bounds__(256) void item_csr(
    const int* __restrict__ bcur, const int* __restrict__ bbase,
    const int* __restrict__ staging, int* __restrict__ rpi,
    float* __restrict__ dinv, int* __restrict__ csr)
{
    __shared__ int hist[256];
    __shared__ int cur[256];
    __shared__ int wsum[4];
    const int b = blockIdx.x;
    const int tid = threadIdx.x, lane = tid & 63, w = tid >> 6;
    const int sbase = b * SLOT;
    const int n = bcur[b] - sbase;
    const int cbase = bbase[b];

    hist[tid] = 0;
    __syncthreads();
    for (int i = tid; i < n; i += 256)
        atomicAdd(&hist[((unsigned)staging[sbase + i]) >> 24], 1);
    __syncthreads();

    int h = hist[tid];
    int incl = h;
    #pragma unroll
    for (int off = 1; off < 64; off <<= 1) {
        int s = __shfl_up(incl, off);
        if (lane >= off) incl += s;
    }
    if (lane == 63) wsum[w] = incl;
    __syncthreads();
    int woff = 0;
    #pragma unroll
    for (int k = 0; k < 4; ++k) woff += (k < w) ? wsum[k] : 0;
    int excl = woff + incl - h;

    int gitem = b * 256 + tid;
    if (gitem < N_ITEMS) {
        rpi[gitem] = cbase + excl;
        dinv[N_USERS + gitem] = rsqrtf((float)h + 1e-7f);
    }
    cur[tid] = cbase + excl;
    __syncthreads();

    for (int i = tid; i < n; i += 256) {
        int e = staging[sbase + i];
        int p = atomicAdd(&cur[((unsigned)e) >> 24], 1);
        csr[p] = e & 0xFFFFFF;
    }
}

// ---- prep: z0[r] = dinv[r] * in_embs[r] in bf16 ----
__global__ __launch_bounds__(256) void prep0(
    const float* __restrict__ init, const float* __restrict__ dinv,
    unsigned short* __restrict__ z)
{
    int i = blockIdx.x * 256 + threadIdx.x;     // one float4 / ushort4 per thread
    if (i >= N_NODES * D / 4) return;
    int r = i >> 4;
    float dv = dinv[r];
    float4 x = reinterpret_cast<const float4*>(init)[i];
    ushort4 o;
    o.x = f2bf(x.x * dv); o.y = f2bf(x.y * dv);
    o.z = f2bf(x.z * dv); o.w = f2bf(x.w * dv);
    reinterpret_cast<ushort4*>(z)[i] = o;
}

// ---- fused SpMM + L2-normalize + out accumulate (bf16 z rows) ----
// 256 threads = 4 waves; wave = 4 rows via 16-lane groups; ushort4 per lane.
__global__ __launch_bounds__(256) void spmm_norm(
    const unsigned short* __restrict__ z,
    const int* __restrict__ rpu,
    const int* __restrict__ rpi,
    const int* __restrict__ cols_u,
    const int* __restrict__ csr_col_i,
    const float* __restrict__ dinv,
    const float* __restrict__ init,
    unsigned short* __restrict__ zout,
    float* __restrict__ out,
    float invl, int first, int writez)
{
    const int tid = threadIdx.x;
    const int lane = tid & 63;
    const int g = lane >> 4;
    const int sl = lane & 15;
    const int wave = tid >> 6;
    const int row = blockIdx.x * 16 + wave * 4 + g;
    if (row >= N_NODES) return;
    const int gb = g << 4;

    int beg, end;
    const int* clist;
    if (row < N_USERS) {
        beg = rpu[row]; end = rpu[row + 1]; clist = cols_u;
    } else {
        int v = row - N_USERS;
        beg = rpi[v]; end = rpi[v + 1]; clist = csr_col_i;
    }

    float ax = 0.f, ay = 0.f, az = 0.f, aw = 0.f;
    for (int base = beg; base < end; base += 16) {
        int li = base + sl;
        int c_l = 0;
        if (li < end) c_l = clist[li];
        int nch = min(16, end - base);
        int j = 0;
        for (; j + 4 <= nch; j += 4) {
            int c0 = __shfl(c_l, gb + j + 0);
            int c1 = __shfl(c_l, gb + j + 1);
            int c2 = __shfl(c_l, gb + j + 2);
            int c3 = __shfl(c_l, gb + j + 3);
            ushort4 z0 = reinterpret_cast<const ushort4*>(z + (size_t)c0 * D)[sl];
            ushort4 z1 = reinterpret_cast<const ushort4*>(z + (size_t)c1 * D)[sl];
            ushort4 z2 = reinterpret_cast<const ushort4*>(z + (size_t)c2 * D)[sl];
            ushort4 z3 = reinterpret_cast<const ushort4*>(z + (size_t)c3 * D)[sl];
            ax += bf2f(z0.x); ay += bf2f(z0.y); az += bf2f(z0.z); aw += bf2f(z0.w);
            ax += bf2f(z1.x); ay += bf2f(z1.y); az += bf2f(z1.z); aw += bf2f(z1.w);
            ax += bf2f(z2.x); ay += bf2f(z2.y); az += bf2f(z2.z); aw += bf2f(z2.w);
            ax += bf2f(z3.x); ay += bf2f(z3.y); az += bf2f(z3.z); aw += bf2f(z3.w);
        }
        for (; j < nch; ++j) {
            int c = __shfl(c_l, gb + j);
            ushort4 zv = reinterpret_cast<const ushort4*>(z + (size_t)c * D)[sl];
            ax += bf2f(zv.x); ay += bf2f(zv.y); az += bf2f(zv.z); aw += bf2f(zv.w);
        }
    }

    float ss = ax * ax + ay * ay + az * az + aw * aw;
    #pragma unroll
    for (int off = 8; off > 0; off >>= 1)
        ss += __shfl_xor(ss, off);
    float nrm = sqrtf(ss);
    float rinv = 1.0f / fmaxf(nrm, 1e-12f);

    float xnx = ax * rinv, xny = ay * rinv, xnz = az * rinv, xnw = aw * rinv;

    size_t idx = (size_t)row * D + sl * 4;
    if (writez) {
        float dv = dinv[row];
        ushort4 zo;
        zo.x = f2bf(xnx * dv); zo.y = f2bf(xny * dv);
        zo.z = f2bf(xnz * dv); zo.w = f2bf(xnw * dv);
        reinterpret_cast<ushort4*>(zout + (size_t)row * D)[sl] = zo;
    }

    float4 bo = first ? *reinterpret_cast<const float4*>(init + idx)
                      : *reinterpret_cast<const float4*>(out + idx);
    bo.x += xnx * invl; bo.y += xny * invl;
    bo.z += xnz * invl; bo.w += xnw * invl;
    *reinterpret_cast<float4*>(out + idx) = bo;
}

extern "C" void kernel_launch(void* const* d_in, const int* in_sizes, int n_in,
                              void* d_out, int out_size, void* d_ws, size_t ws_size,
                              hipStream_t stream) {
    const float* in_embs = (const float*)d_in[0];
    const int*   rows    = (const int*)d_in[1];
    const int*   cols    = (const int*)d_in[2];
    float* out = (float*)d_out;

    const int E  = in_sizes[1];
    const int Eh = E / 2;
    const size_t z_bytes = (size_t)N_NODES * D * sizeof(unsigned short); // 19.2 MB

    auto align256 = [](size_t x) { return (x + 255) & ~(size_t)255; };
    char* p = (char*)d_ws;
    unsigned short* zP = (unsigned short*)p; p += align256(z_bytes);
    unsigned short* zQ = (unsigned short*)p; p += align256(z_bytes);
    int*   csr_col_i = (int*)p;   p += align256((size_t)Eh * sizeof(int));
    int*   rpu       = (int*)p;   p += align256((size_t)(N_USERS + 1) * sizeof(int));
    int*   rpi       = (int*)p;   p += align256((size_t)(N_ITEMS + 1) * sizeof(int));
    float* dinv      = (float*)p; p += align256((size_t)N_NODES * sizeof(float));
    int*   bcur      = (int*)p;   p += align256(256 * sizeof(int));
    int*   bbase     = (int*)p;   p += align256(256 * sizeof(int));
    // staging aliases zP (9.6 MB < 19.2 MB); consumed by item_csr before prep0.
    int*   staging   = (int*)zP;

    // --- CSR build ---
    init_cursors<<<1, 256, 0, stream>>>(bcur);
    bucket_scatter<<<(Eh + EPB - 1) / EPB, 256, 0, stream>>>(rows, cols, bcur, staging, Eh);
    scan_buckets<<<1, 256, 0, stream>>>(bcur, bbase, rpi);
    item_csr<<<NBK, 256, 0, stream>>>(bcur, bbase, staging, rpi, dinv, csr_col_i);
    rpu_kernel<<<(N_USERS + 256) / 256, 256, 0, stream>>>(rows, rpu, Eh);
    dinv_users<<<(N_USERS + 255) / 256, 256, 0, stream>>>(rpu, dinv);
    prep0<<<(N_NODES * D / 4 + 255) / 256, 256, 0, stream>>>(in_embs, dinv, zP);

    // --- 3 propagation layers ---
    const int spmm_blocks = (N_NODES + 15) / 16;
    unsigned short* zin = zP;
    unsigned short* zout = zQ;
    for (int layer = 0; layer < 3; ++layer) {
        int last = (layer == 2);
        spmm_norm<<<spmm_blocks, 256, 0, stream>>>(
            zin, rpu, rpi, cols, csr_col_i, dinv, in_embs, zout, out,
            1.0f / (layer + 1), layer == 0 ? 1 : 0, last ? 0 : 1);
        unsigned short* t = zin; zin = zout; zout = t;
    }
}

// Round 7
// 226.783 us; speedup vs baseline: 41.5159x; 1.1056x over previous
//
#include <hip/hip_runtime.h>
#include <hip/hip_bf16.h>

// LightGCN on MI355X — round 7.
// z[c] = dinv[c]*x_norm[c] in bf16; SpMM = pure gather-sum (no weights).
// Layers 0/1 write only z (no out RMW); last layer reconstructs xn1, xn2
// from z1, z2 and writes out = init + xn1 + xn2/2 + xn3/3 in one pass.
// Gathers: 8-lane groups, uint4 (16 B) per lane, full 8-neighbor unroll.
// Build: user CSR free (sorted edges); item CSR via LDS bucket sort;
// launch-fused (7 dispatches total).

constexpr int N_USERS = 100000;
constexpr int N_ITEMS = 50000;
constexpr int N_NODES = N_USERS + N_ITEMS;
constexpr int D = 64;
constexpr int NBK  = 196;
constexpr int SLOT = 12288;
constexpr int EPB  = 16384;

__device__ inline unsigned f2bf(float f) {
    unsigned u = __float_as_uint(f);
    u += 0x7FFFu + ((u >> 16) & 1u);   // RNE
    return u >> 16;
}
__device__ inline float bflo(unsigned u) { return __uint_as_float(u << 16); }
__device__ inline float bfhi(unsigned u) { return __uint_as_float(u & 0xFFFF0000u); }

__device__ inline int lower_bound(const int* __restrict__ a, int n, int key) {
    int lo = 0, hi = n;
    while (lo < hi) { int m = (lo + hi) >> 1; if (a[m] < key) lo = m + 1; else hi = m; }
    return lo;
}

// ---- user row_ptr (binary search on sorted rows) + user dinv + bcur init ----
__global__ __launch_bounds__(256) void rpu_kernel(
    const int* __restrict__ rows, int* __restrict__ rpu,
    float* __restrict__ dinv, int* __restrict__ bcur, int Eh)
{
    if (blockIdx.x == 0 && threadIdx.x < NBK) bcur[threadIdx.x] = threadIdx.x * SLOT;
    int i = blockIdx.x * 256 + threadIdx.x;
    if (i > N_USERS) return;
    int lo = lower_bound(rows, Eh, i);
    rpu[i] = lo;
    int lane = threadIdx.x & 63;
    int nxt = __shfl_down(lo, 1);
    if (lane == 63 || i >= N_USERS)
        nxt = (i < N_USERS) ? lower_bound(rows, Eh, i + 1) : lo;
    if (i < N_USERS)
        dinv[i] = rsqrtf((float)(nxt - lo) + 1e-7f);
}

// ---- pass 1: bucket scatter of (u, vlocal) from the first edge half ----
__global__ __launch_bounds__(256) void bucket_scatter(
    const int* __restrict__ rows, const int* __restrict__ cols,
    int* __restrict__ bcur, int* __restrict__ staging, int Eh)
{
    __shared__ int hist[256];
    const int tid = threadIdx.x;
    const int base = blockIdx.x * EPB;
    const int nEdge = min(EPB, Eh - base);
    if (nEdge <= 0) return;

    hist[tid] = 0;
    __syncthreads();

    for (int s = 0; s < 16; ++s) {
        int o = s * 1024 + tid * 4;
        if (o + 3 < nEdge) {
            int4 c4 = *reinterpret_cast<const int4*>(cols + base + o);
            atomicAdd(&hist[(c4.x - N_USERS) >> 8], 1);
            atomicAdd(&hist[(c4.y - N_USERS) >> 8], 1);
            atomicAdd(&hist[(c4.z - N_USERS) >> 8], 1);
            atomicAdd(&hist[(c4.w - N_USERS) >> 8], 1);
        } else if (o < nEdge) {
            for (int k = o; k < nEdge; ++k)
                atomicAdd(&hist[(cols[base + k] - N_USERS) >> 8], 1);
        }
    }
    __syncthreads();

    if (tid < NBK) {
        int h = hist[tid];
        hist[tid] = (h > 0) ? atomicAdd(&bcur[tid], h) : 0;
    }
    __syncthreads();

    for (int s = 0; s < 16; ++s) {
        int o = s * 1024 + tid * 4;
        if (o + 3 < nEdge) {
            int4 c4 = *reinterpret_cast<const int4*>(cols + base + o);
            int4 u4 = *reinterpret_cast<const int4*>(rows + base + o);
            int v, p;
            v = c4.x - N_USERS; p = atomicAdd(&hist[v >> 8], 1);
            staging[p] = ((v & 255) << 24) | u4.x;
            v = c4.y - N_USERS; p = atomicAdd(&hist[v >> 8], 1);
            staging[p] = ((v & 255) << 24) | u4.y;
            v = c4.z - N_USERS; p = atomicAdd(&hist[v >> 8], 1);
            staging[p] = ((v & 255) << 24) | u4.z;
            v = c4.w - N_USERS; p = atomicAdd(&hist[v >> 8], 1);
            staging[p] = ((v & 255) << 24) | u4.w;
        } else if (o < nEdge) {
            for (int k = o; k < nEdge; ++k) {
                int v = cols[base + k] - N_USERS;
                int u = rows[base + k];
                int p = atomicAdd(&hist[v >> 8], 1);
                staging[p] = ((v & 255) << 24) | u;
            }
        }
    }
}

// ---- pass 2: per-bucket sort -> item CSR + rpi + item dinv (scan fused) ----
__global__ __launch_bounds__(256) void item_csr(
    const int* __restrict__ bcur, const int* __restrict__ staging,
    int* __restrict__ rpi, float* __restrict__ dinv, int* __restrict__ csr)
{
    __shared__ int hist[256];
    __shared__ int cur[256];
    __shared__ int wsum[4];
    __shared__ int s_cbase;
    const int b = blockIdx.x;
    const int tid = threadIdx.x, lane = tid & 63, w = tid >> 6;

    // fused exclusive scan of all bucket totals (each block redundantly)
    int tot = (tid < NBK) ? (bcur[tid] - tid * SLOT) : 0;
    int incl = tot;
    #pragma unroll
    for (int off = 1; off < 64; off <<= 1) {
        int s = __shfl_up(incl, off);
        if (lane >= off) incl += s;
    }
    if (lane == 63) wsum[w] = incl;
    __syncthreads();
    int woff = 0;
    #pragma unroll
    for (int k = 0; k < 4; ++k) woff += (k < w) ? wsum[k] : 0;
    int excl = woff + incl - tot;
    if (tid == b) s_cbase = excl;
    if (b == 0 && tid == NBK - 1) rpi[N_ITEMS] = excl + tot;
    __syncthreads();

    const int sbase = b * SLOT;
    const int n = bcur[b] - sbase;
    const int cbase = s_cbase;

    hist[tid] = 0;
    __syncthreads();
    for (int i = tid; i < n; i += 256)
        atomicAdd(&hist[((unsigned)staging[sbase + i]) >> 24], 1);
    __syncthreads();

    int h = hist[tid];
    int incl2 = h;
    #pragma unroll
    for (int off = 1; off < 64; off <<= 1) {
        int s = __shfl_up(incl2, off);
        if (lane >= off) incl2 += s;
    }
    if (lane == 63) wsum[w] = incl2;
    __syncthreads();
    int woff2 = 0;
    #pragma unroll
    for (int k = 0; k < 4; ++k) woff2 += (k < w) ? wsum[k] : 0;
    int excl2 = woff2 + incl2 - h;

    int gitem = b * 256 + tid;
    if (gitem < N_ITEMS) {
        rpi[gitem] = cbase + excl2;
        dinv[N_USERS + gitem] = rsqrtf((float)h + 1e-7f);
    }
    cur[tid] = cbase + excl2;
    __syncthreads();

    for (int i = tid; i < n; i += 256) {
        int e = staging[sbase + i];
        int p = atomicAdd(&cur[((unsigned)e) >> 24], 1);
        csr[p] = e & 0xFFFFFF;
    }
}

// ---- prep: z0[r] = dinv[r] * in_embs[r] in bf16 ----
__global__ __launch_bounds__(256) void prep0(
    const float* __restrict__ init, const float* __restrict__ dinv,
    unsigned short* __restrict__ z)
{
    int i = blockIdx.x * 256 + threadIdx.x;     // one float4 -> 4 bf16 per thread
    if (i >= N_NODES * D / 4) return;
    int r = i >> 4;
    float dv = dinv[r];
    float4 x = reinterpret_cast<const float4*>(init)[i];
    unsigned lo0 = f2bf(x.x * dv), hi0 = f2bf(x.y * dv);
    unsigned lo1 = f2bf(x.z * dv), hi1 = f2bf(x.w * dv);
    uint2 o; o.x = lo0 | (hi0 << 16); o.y = lo1 | (hi1 << 16);
    reinterpret_cast<uint2*>(z)[i] = o;
}

// ---- fused SpMM + L2-normalize (+ z write | final combine) ----
// 256 threads = 4 waves = 32 rows; 8-lane groups; uint4 (8 dims) per lane.
#define ACC8(r) do { \
    a0 += bflo(r.x); a1 += bfhi(r.x); \
    a2 += bflo(r.y); a3 += bfhi(r.y); \
    a4 += bflo(r.z); a5 += bfhi(r.z); \
    a6 += bflo(r.w); a7 += bfhi(r.w); } while (0)

template<int LAST>
__global__ __launch_bounds__(256) void spmm8(
    const unsigned short* __restrict__ z,
    const int* __restrict__ rpu,
    const int* __restrict__ rpi,
    const int* __restrict__ cols_u,
    const int* __restrict__ csr_col_i,
    const float* __restrict__ dinv,
    unsigned short* __restrict__ zout,
    const unsigned short* z1,
    const unsigned short* z2,
    const float* __restrict__ init,
    float* __restrict__ out)
{
    const int tid = threadIdx.x;
    const int lane = tid & 63;
    const int g  = lane >> 3;
    const int sl = lane & 7;
    const int wave = tid >> 6;
    const int row = blockIdx.x * 32 + wave * 8 + g;
    if (row >= N_NODES) return;
    const int gb = g << 3;

    int beg, end;
    const int* clist;
    if (row < N_USERS) {
        beg = rpu[row]; end = rpu[row + 1]; clist = cols_u;
    } else {
        int v = row - N_USERS;
        beg = rpi[v]; end = rpi[v + 1]; clist = csr_col_i;
    }

    float a0=0.f,a1=0.f,a2=0.f,a3=0.f,a4=0.f,a5=0.f,a6=0.f,a7=0.f;
    const unsigned short* zs = z + (size_t)sl * 8;

    int j = beg;
    for (; j + 8 <= end; j += 8) {
        int c_l = clist[j + sl];
        int c0 = __shfl(c_l, gb + 0);
        int c1 = __shfl(c_l, gb + 1);
        int c2 = __shfl(c_l, gb + 2);
        int c3 = __shfl(c_l, gb + 3);
        int c4 = __shfl(c_l, gb + 4);
        int c5 = __shfl(c_l, gb + 5);
        int c6 = __shfl(c_l, gb + 6);
        int c7 = __shfl(c_l, gb + 7);
        uint4 r0 = *reinterpret_cast<const uint4*>(zs + (size_t)c0 * D);
        uint4 r1 = *reinterpret_cast<const uint4*>(zs + (size_t)c1 * D);
        uint4 r2 = *reinterpret_cast<const uint4*>(zs + (size_t)c2 * D);
        uint4 r3 = *reinterpret_cast<const uint4*>(zs + (size_t)c3 * D);
        uint4 r4 = *reinterpret_cast<const uint4*>(zs + (size_t)c4 * D);
        uint4 r5 = *reinterpret_cast<const uint4*>(zs + (size_t)c5 * D);
        uint4 r6 = *reinterpret_cast<const uint4*>(zs + (size_t)c6 * D);
        uint4 r7 = *reinterpret_cast<const uint4*>(zs + (size_t)c7 * D);
        ACC8(r0); ACC8(r1); ACC8(r2); ACC8(r3);
        ACC8(r4); ACC8(r5); ACC8(r6); ACC8(r7);
    }
    int rem = end - j;
    if (rem > 0) {
        int c_l = (j + sl < end) ? clist[j + sl] : 0;
        for (int k = 0; k < rem; ++k) {
            int c = __shfl(c_l, gb + k);
            uint4 r = *reinterpret_cast<const uint4*>(zs + (size_t)c * D);
            ACC8(r);
        }
    }

    float ss = a0*a0 + a1*a1 + a2*a2 + a3*a3 + a4*a4 + a5*a5 + a6*a6 + a7*a7;
    ss += __shfl_xor(ss, 1);
    ss += __shfl_xor(ss, 2);
    ss += __shfl_xor(ss, 4);
    float rinv = 1.0f / fmaxf(sqrtf(ss), 1e-12f);

    size_t idx = (size_t)row * D + (size_t)sl * 8;
    if (!LAST) {
        float s = rinv * dinv[row];
        uint4 zo;
        zo.x = f2bf(a0 * s) | (f2bf(a1 * s) << 16);
        zo.y = f2bf(a2 * s) | (f2bf(a3 * s) << 16);
        zo.z = f2bf(a4 * s) | (f2bf(a5 * s) << 16);
        zo.w = f2bf(a6 * s) | (f2bf(a7 * s) << 16);
        *reinterpret_cast<uint4*>(zout + idx) = zo;
    } else {
        float recip = 1.0f / dinv[row];         // = sqrt(deg + eps)
        float k1 = recip, k2 = 0.5f * recip, k3 = rinv * (1.0f / 3.0f);
        uint4 w1 = *reinterpret_cast<const uint4*>(z1 + idx);
        uint4 w2 = *reinterpret_cast<const uint4*>(z2 + idx);
        const float4* ip = reinterpret_cast<const float4*>(init + idx);
        float4 o0 = ip[0], o1 = ip[1];
        o0.x += bflo(w1.x) * k1 + bflo(w2.x) * k2 + a0 * k3;
        o0.y += bfhi(w1.x) * k1 + bfhi(w2.x) * k2 + a1 * k3;
        o0.z += bflo(w1.y) * k1 + bflo(w2.y) * k2 + a2 * k3;
        o0.w += bfhi(w1.y) * k1 + bfhi(w2.y) * k2 + a3 * k3;
        o1.x += bflo(w1.z) * k1 + bflo(w2.z) * k2 + a4 * k3;
        o1.y += bfhi(w1.z) * k1 + bfhi(w2.z) * k2 + a5 * k3;
        o1.z += bflo(w1.w) * k1 + bflo(w2.w) * k2 + a6 * k3;
        o1.w += bfhi(w1.w) * k1 + bfhi(w2.w) * k2 + a7 * k3;
        float4* op = reinterpret_cast<float4*>(out + idx);
        op[0] = o0; op[1] = o1;
    }
}

extern "C" void kernel_launch(void* const* d_in, const int* in_sizes, int n_in,
                              void* d_out, int out_size, void* d_ws, size_t ws_size,
                              hipStream_t stream) {
    const float* in_embs = (const float*)d_in[0];
    const int*   rows    = (const int*)d_in[1];
    const int*   cols    = (const int*)d_in[2];
    float* out = (float*)d_out;

    const int E  = in_sizes[1];
    const int Eh = E / 2;
    const size_t z_bytes = (size_t)N_NODES * D * sizeof(unsigned short); // 19.2 MB

    auto align256 = [](size_t x) { return (x + 255) & ~(size_t)255; };
    char* p = (char*)d_ws;
    unsigned short* zP = (unsigned short*)p; p += align256(z_bytes);
    unsigned short* zQ = (unsigned short*)p; p += align256(z_bytes);
    int*   csr_col_i = (int*)p;   p += align256((size_t)Eh * sizeof(int));
    int*   rpu       = (int*)p;   p += align256((size_t)(N_USERS + 1) * sizeof(int));
    int*   rpi       = (int*)p;   p += align256((size_t)(N_ITEMS + 1) * sizeof(int));
    float* dinv      = (float*)p; p += align256((size_t)N_NODES * sizeof(float));
    int*   bcur      = (int*)p;   p += align256(256 * sizeof(int));
    // staging aliases zP (9.63 MB < 19.2 MB); consumed by item_csr before prep0
    int*   staging   = (int*)zP;

    // --- CSR build (4 dispatches) ---
    rpu_kernel<<<(N_USERS + 256) / 256, 256, 0, stream>>>(rows, rpu, dinv, bcur, Eh);
    bucket_scatter<<<(Eh + EPB - 1) / EPB, 256, 0, stream>>>(rows, cols, bcur, staging, Eh);
    item_csr<<<NBK, 256, 0, stream>>>(bcur, staging, rpi, dinv, csr_col_i);
    prep0<<<(N_NODES * D / 4 + 255) / 256, 256, 0, stream>>>(in_embs, dinv, zP);

    // --- 3 propagation layers ---
    const int grid = (N_NODES + 31) / 32;
    // L0: gather zP -> z1 in zQ
    spmm8<0><<<grid, 256, 0, stream>>>(zP, rpu, rpi, cols, csr_col_i, dinv,
                                       zQ, nullptr, nullptr, nullptr, nullptr);
    // L1: gather zQ -> z2 in zP (z0 dead)
    spmm8<0><<<grid, 256, 0, stream>>>(zQ, rpu, rpi, cols, csr_col_i, dinv,
                                       zP, nullptr, nullptr, nullptr, nullptr);
    // L2: gather zP (z2); out = init + z1/dinv + (z2/dinv)/2 + xn3/3
    spmm8<1><<<grid, 256, 0, stream>>>(zP, rpu, rpi, cols, csr_col_i, dinv,
                                       nullptr, zQ, zP, in_embs, out);
}